// Round 2
// baseline (470.830 us; speedup 1.0000x reference)
//
#include <hip/hip_runtime.h>

#define D 100
#define YSTRIDE 128  // y row stride in bf16 elements (256 B, 2 aligned cache lines)

// ---------------- CSR build ----------------

__global__ __launch_bounds__(256) void k_hist(const int* __restrict__ dst, int* __restrict__ cnt, int E) {
    int e = blockIdx.x * 256 + threadIdx.x;
    if (e < E) atomicAdd(&cnt[dst[e]], 1);
}

__global__ __launch_bounds__(256) void k_blocksum(const int* __restrict__ cnt, int* __restrict__ bsum, int n) {
    __shared__ int s[256];
    int i = blockIdx.x * 256 + threadIdx.x;
    s[threadIdx.x] = (i < n) ? cnt[i] : 0;
    __syncthreads();
    for (int off = 128; off; off >>= 1) {
        if (threadIdx.x < off) s[threadIdx.x] += s[threadIdx.x + off];
        __syncthreads();
    }
    if (threadIdx.x == 0) bsum[blockIdx.x] = s[0];
}

// single block: exclusive scan of nb (<=256) block sums
__global__ __launch_bounds__(256) void k_scan_bsum(const int* __restrict__ bsum, int* __restrict__ boff, int nb) {
    __shared__ int s[256];
    int v = (threadIdx.x < nb) ? bsum[threadIdx.x] : 0;
    s[threadIdx.x] = v;
    __syncthreads();
    for (int off = 1; off < 256; off <<= 1) {
        int t = (threadIdx.x >= off) ? s[threadIdx.x - off] : 0;
        __syncthreads();
        s[threadIdx.x] += t;
        __syncthreads();
    }
    if (threadIdx.x < nb) boff[threadIdx.x] = s[threadIdx.x] - v;  // exclusive
}

__global__ __launch_bounds__(256) void k_scan_write(const int* __restrict__ cnt, const int* __restrict__ boff,
                                                    int* __restrict__ rowptr, int n, int E) {
    __shared__ int s[256];
    int i = blockIdx.x * 256 + threadIdx.x;
    int v = (i < n) ? cnt[i] : 0;
    s[threadIdx.x] = v;
    __syncthreads();
    for (int off = 1; off < 256; off <<= 1) {
        int t = (threadIdx.x >= off) ? s[threadIdx.x - off] : 0;
        __syncthreads();
        s[threadIdx.x] += t;
        __syncthreads();
    }
    if (i < n) rowptr[i] = boff[blockIdx.x] + s[threadIdx.x] - v;
    if (blockIdx.x == 0 && threadIdx.x == 0) rowptr[n] = E;
}

// cur[] is pre-initialized to rowptr[0..N) via d2d copy
__global__ __launch_bounds__(256) void k_fill(const int* __restrict__ src, const int* __restrict__ dst,
                                              int* __restrict__ cur, int* __restrict__ col, int E) {
    int e = blockIdx.x * 256 + threadIdx.x;
    if (e >= E) return;
    int d = dst[e];
    int pos = atomicAdd(&cur[d], 1);
    col[pos] = src[e];
}

// ---------------- W transpose: WT[l][k][c] = W[l][c][k] ----------------
__global__ __launch_bounds__(256) void k_wt(const float* __restrict__ W, float* __restrict__ WT, int total) {
    int i = blockIdx.x * 256 + threadIdx.x;
    if (i >= total) return;
    int l = i / (D * D);
    int rem = i - l * (D * D);
    int k = rem / D, c = rem - k * D;
    WT[i] = W[l * D * D + c * D + k];
}

// ---------------- GEMM: y16 = bf16(x @ W^T) ----------------
// One thread per row. WT[k][c] accessed with wave-uniform indices -> scalar
// loads (constant cache), v_fmac with SGPR operand. acc[100] in VGPRs.
__device__ inline unsigned short f2bf(float f) {
    unsigned u = __float_as_uint(f);
    unsigned r = (u + 0x7fffu + ((u >> 16) & 1u)) >> 16;  // RNE
    return (unsigned short)r;
}

__global__ __launch_bounds__(256, 1) void k_gemm(const float* __restrict__ x, const float* __restrict__ WT,
                                                 unsigned short* __restrict__ y16, int N) {
    int r = blockIdx.x * 256 + threadIdx.x;
    if (r >= N) return;

    float acc[D];
#pragma unroll
    for (int c = 0; c < D; c++) acc[c] = 0.f;

    const float4* xr4 = (const float4*)(x + (long)r * D);
#pragma unroll 1
    for (int k4 = 0; k4 < D / 4; k4++) {
        float4 xq = xr4[k4];
#pragma unroll
        for (int j = 0; j < 4; j++) {
            float xk = (j == 0) ? xq.x : (j == 1) ? xq.y : (j == 2) ? xq.z : xq.w;
            const float* w = WT + (k4 * 4 + j) * D;  // wave-uniform address
#pragma unroll
            for (int c = 0; c < D; c++) acc[c] += xk * w[c];
        }
    }

    unsigned int* yr = (unsigned int*)(y16 + (long)r * YSTRIDE);
#pragma unroll
    for (int c = 0; c < D; c += 2) {
        unsigned int lo = f2bf(acc[c]);
        unsigned int hi = f2bf(acc[c + 1]);
        yr[c >> 1] = lo | (hi << 16);
    }
}

// ---------------- fused SpMM + row-normalize + avg update ----------------
// One wave per node. Lanes 0..49 each own 2 dims (one uint = 2 bf16).
__global__ __launch_bounds__(256) void k_spmm(const unsigned short* __restrict__ y16,
                                              const int* __restrict__ rowptr,
                                              const int* __restrict__ col,
                                              const float* __restrict__ basein,
                                              float basescale, float invlp1, int write_x,
                                              float* __restrict__ xnew, float* __restrict__ avg, int N) {
    int wave = threadIdx.x >> 6;
    int lane = threadIdx.x & 63;
    int d = blockIdx.x * 4 + wave;
    if (d >= N) return;

    int beg = rowptr[d], end = rowptr[d + 1];
    bool act = lane < (D / 2);

    float2 acc = make_float2(0.f, 0.f);
    if (act) {  // self loop
        unsigned int v = ((const unsigned int*)(y16 + (long)d * YSTRIDE))[lane];
        acc.x = __uint_as_float(v << 16);
        acc.y = __uint_as_float(v & 0xffff0000u);
    }
    for (int base = beg; base < end; base += 64) {
        int m = min(64, end - base);
        int c = (lane < m) ? col[base + lane] : 0;
        for (int j = 0; j < m; j++) {
            int s = __shfl(c, j);
            if (act) {
                unsigned int v = ((const unsigned int*)(y16 + (long)s * YSTRIDE))[lane];
                acc.x += __uint_as_float(v << 16);
                acc.y += __uint_as_float(v & 0xffff0000u);
            }
        }
    }
    float dinv = 1.f / (float)(end - beg + 1);
    acc.x *= dinv;
    acc.y *= dinv;

    float nsq = act ? (acc.x * acc.x + acc.y * acc.y) : 0.f;
    for (int off = 32; off; off >>= 1) nsq += __shfl_xor(nsq, off);
    float scale = invlp1 / fmaxf(sqrtf(nsq), 1e-12f);

    if (act) {
        if (write_x) *(float2*)(xnew + (long)d * D + lane * 2) = acc;
        float2 b = *(const float2*)(basein + (long)d * D + lane * 2);
        float2 o;
        o.x = b.x * basescale + acc.x * scale;
        o.y = b.y * basescale + acc.y * scale;
        *(float2*)(avg + (long)d * D + lane * 2) = o;
    }
}

// ---------------- launcher ----------------

extern "C" void kernel_launch(void* const* d_in, const int* in_sizes, int n_in,
                              void* d_out, int out_size, void* d_ws, size_t ws_size,
                              hipStream_t stream) {
    const float* features = (const float*)d_in[0];
    const float* W        = (const float*)d_in[1];
    const int*   src      = (const int*)d_in[2];
    const int*   dstv     = (const int*)d_in[3];

    int N = in_sizes[0] / D;            // 50000
    int E = in_sizes[2];                // 800000
    int L = in_sizes[1] / (D * D);      // 2
    float invlp1 = 1.f / (float)(L + 1);

    char*  ws  = (char*)d_ws;
    size_t off = 0;
    auto alloc = [&](size_t bytes) -> void* {
        void* p = (void*)(ws + off);
        off += (bytes + 255) & ~(size_t)255;
        return p;
    };
    unsigned short* y16   = (unsigned short*)alloc((size_t)N * YSTRIDE * sizeof(unsigned short));
    float*          xbuf  = (float*)alloc((size_t)N * D * sizeof(float));
    float*          WT    = (float*)alloc((size_t)L * D * D * sizeof(float));
    int*            colb  = (int*)alloc((size_t)E * sizeof(int));
    int*            cnt   = (int*)alloc((size_t)N * sizeof(int));
    int*            rowptr= (int*)alloc((size_t)(N + 1) * sizeof(int));
    int*            cur   = (int*)alloc((size_t)N * sizeof(int));
    int             NB    = (N + 255) / 256;
    int*            bsum  = (int*)alloc((size_t)NB * sizeof(int));
    int*            boff  = (int*)alloc((size_t)NB * sizeof(int));

    // CSR build (per call — ws is re-poisoned before every timed launch)
    hipMemsetAsync(cnt, 0, (size_t)N * sizeof(int), stream);
    k_hist<<<(E + 255) / 256, 256, 0, stream>>>(dstv, cnt, E);
    k_blocksum<<<NB, 256, 0, stream>>>(cnt, bsum, N);
    k_scan_bsum<<<1, 256, 0, stream>>>(bsum, boff, NB);
    k_scan_write<<<NB, 256, 0, stream>>>(cnt, boff, rowptr, N, E);
    hipMemcpyAsync(cur, rowptr, (size_t)N * sizeof(int), hipMemcpyDeviceToDevice, stream);
    k_fill<<<(E + 255) / 256, 256, 0, stream>>>(src, dstv, cur, colb, E);
    k_wt<<<(L * D * D + 255) / 256, 256, 0, stream>>>(W, WT, L * D * D);

    float* out = (float*)d_out;
    const float* xin = features;
    for (int l = 0; l < L; l++) {
        k_gemm<<<(N + 255) / 256, 256, 0, stream>>>(xin, WT + (size_t)l * D * D, y16, N);
        const float* basein = (l == 0) ? features : out;
        float bscale        = (l == 0) ? invlp1 : 1.f;
        int   write_x       = (l < L - 1) ? 1 : 0;
        k_spmm<<<(N + 3) / 4, 256, 0, stream>>>(y16, rowptr, colb, basein, bscale, invlp1, write_x,
                                                xbuf, out, N);
        xin = xbuf;
    }
}

// Round 3
// 332.629 us; speedup vs baseline: 1.4155x; 1.4155x over previous
//
#include <hip/hip_runtime.h>

#define D 100
#define YSTRIDE 128  // y row stride in bf16 elements (256 B, 2 aligned cache lines)

typedef __attribute__((ext_vector_type(8))) short bf8v;
typedef __attribute__((ext_vector_type(4))) float f4v;

__device__ inline unsigned short f2bf(float f) {
    unsigned u = __float_as_uint(f);
    return (unsigned short)((u + 0x7fffu + ((u >> 16) & 1u)) >> 16);  // RNE
}

// ---------------- CSR build ----------------

__global__ __launch_bounds__(256) void k_hist(const int* __restrict__ dst, int* __restrict__ cnt, int E) {
    int e = blockIdx.x * 256 + threadIdx.x;
    if (e < E) atomicAdd(&cnt[dst[e]], 1);
}

__global__ __launch_bounds__(256) void k_blocksum(const int* __restrict__ cnt, int* __restrict__ bsum, int n) {
    __shared__ int s[256];
    int i = blockIdx.x * 256 + threadIdx.x;
    s[threadIdx.x] = (i < n) ? cnt[i] : 0;
    __syncthreads();
    for (int off = 128; off; off >>= 1) {
        if (threadIdx.x < off) s[threadIdx.x] += s[threadIdx.x + off];
        __syncthreads();
    }
    if (threadIdx.x == 0) bsum[blockIdx.x] = s[0];
}

// single block: exclusive scan of nb (<=256) block sums
__global__ __launch_bounds__(256) void k_scan_bsum(const int* __restrict__ bsum, int* __restrict__ boff, int nb) {
    __shared__ int s[256];
    int v = (threadIdx.x < nb) ? bsum[threadIdx.x] : 0;
    s[threadIdx.x] = v;
    __syncthreads();
    for (int off = 1; off < 256; off <<= 1) {
        int t = (threadIdx.x >= off) ? s[threadIdx.x - off] : 0;
        __syncthreads();
        s[threadIdx.x] += t;
        __syncthreads();
    }
    if (threadIdx.x < nb) boff[threadIdx.x] = s[threadIdx.x] - v;  // exclusive
}

__global__ __launch_bounds__(256) void k_scan_write(const int* __restrict__ cnt, const int* __restrict__ boff,
                                                    int* __restrict__ rowptr, int n, int E) {
    __shared__ int s[256];
    int i = blockIdx.x * 256 + threadIdx.x;
    int v = (i < n) ? cnt[i] : 0;
    s[threadIdx.x] = v;
    __syncthreads();
    for (int off = 1; off < 256; off <<= 1) {
        int t = (threadIdx.x >= off) ? s[threadIdx.x - off] : 0;
        __syncthreads();
        s[threadIdx.x] += t;
        __syncthreads();
    }
    if (i < n) rowptr[i] = boff[blockIdx.x] + s[threadIdx.x] - v;
    if (blockIdx.x == 0 && threadIdx.x == 0) rowptr[n] = E;
}

// cur[] is pre-initialized to rowptr[0..N) via d2d copy
__global__ __launch_bounds__(256) void k_fill(const int* __restrict__ src, const int* __restrict__ dst,
                                              int* __restrict__ cur, int* __restrict__ col, int E) {
    int e = blockIdx.x * 256 + threadIdx.x;
    if (e >= E) return;
    int d = dst[e];
    int pos = atomicAdd(&cur[d], 1);
    col[pos] = src[e];
}

// ---------------- MFMA GEMM: y16 = bf16(x @ W^T) ----------------
// One wave per 16-row tile. K=100 padded to 128 (4 steps of 32).
// N=100 padded to 112 (7 col-tiles of 16). acc: 7 x f32x4 = 28 VGPRs.
// A frag: A[m=lane&15][k=quad*8+j]   (x row m, 8 contiguous k)
// B frag: B[k=quad*8+j][n=lane&15]   = W[n][k] -> 8 contiguous floats of W row n
// C/D   : C[row=quad*4+i][col=lane&15]
__global__ __launch_bounds__(256) void k_gemm_mfma(const float* __restrict__ x,
                                                   const float* __restrict__ W,
                                                   unsigned short* __restrict__ y16, int N) {
    int wave = threadIdx.x >> 6;
    int lane = threadIdx.x & 63;
    int quad = lane >> 4;
    int l16  = lane & 15;
    int rowbase = (blockIdx.x * 4 + wave) * 16;
    if (rowbase >= N) return;

    // ---- A fragments (4 k-steps) from fp32 x ----
    bf8v afrag[4];
    const float* xr = x + (long)(rowbase + l16) * D;
#pragma unroll
    for (int kt = 0; kt < 4; kt++) {
        int k0 = kt * 32 + quad * 8;
        union { bf8v v; unsigned short u[8]; } a;
        if (k0 + 8 <= D) {
            float4 p = *(const float4*)(xr + k0);
            float4 q = *(const float4*)(xr + k0 + 4);
            a.u[0] = f2bf(p.x); a.u[1] = f2bf(p.y); a.u[2] = f2bf(p.z); a.u[3] = f2bf(p.w);
            a.u[4] = f2bf(q.x); a.u[5] = f2bf(q.y); a.u[6] = f2bf(q.z); a.u[7] = f2bf(q.w);
        } else {
#pragma unroll
            for (int j = 0; j < 8; j++) a.u[j] = (k0 + j < D) ? f2bf(xr[k0 + j]) : (unsigned short)0;
        }
        afrag[kt] = a.v;
    }

    // ---- per col-tile: load B frags from W rows, MFMA ----
    f4v acc[7];
#pragma unroll
    for (int nt = 0; nt < 7; nt++) acc[nt] = (f4v){0.f, 0.f, 0.f, 0.f};

#pragma unroll
    for (int nt = 0; nt < 7; nt++) {
        int ng = nt * 16 + l16;          // W row (output col)
        bool vn = ng < D;
        const float* wr = W + (long)ng * D;
#pragma unroll
        for (int kt = 0; kt < 4; kt++) {
            int k0 = kt * 32 + quad * 8;
            union { bf8v v; unsigned short u[8]; } b;
            if (vn && (k0 + 8 <= D)) {
                float4 p = *(const float4*)(wr + k0);
                float4 q = *(const float4*)(wr + k0 + 4);
                b.u[0] = f2bf(p.x); b.u[1] = f2bf(p.y); b.u[2] = f2bf(p.z); b.u[3] = f2bf(p.w);
                b.u[4] = f2bf(q.x); b.u[5] = f2bf(q.y); b.u[6] = f2bf(q.z); b.u[7] = f2bf(q.w);
            } else {
#pragma unroll
                for (int j = 0; j < 8; j++)
                    b.u[j] = (vn && (k0 + j < D)) ? f2bf(wr[k0 + j]) : (unsigned short)0;
            }
            acc[nt] = __builtin_amdgcn_mfma_f32_16x16x32_bf16(afrag[kt], b.v, acc[nt], 0, 0, 0);
        }
    }

    // ---- store C -> y16 (bf16, YSTRIDE-padded rows) ----
    unsigned short* yr = y16 + (long)rowbase * YSTRIDE;
#pragma unroll
    for (int nt = 0; nt < 7; nt++) {
        int cc = nt * 16 + l16;
        if (cc < D) {
#pragma unroll
            for (int i = 0; i < 4; i++) {
                int rr = quad * 4 + i;
                yr[(long)rr * YSTRIDE + cc] = f2bf(acc[nt][i]);
            }
        }
    }
}

// ---------------- fused SpMM + row-normalize + avg update ----------------
// One wave per node. Lanes 0..49 each own 2 dims (one uint = 2 bf16).
__global__ __launch_bounds__(256) void k_spmm(const unsigned short* __restrict__ y16,
                                              const int* __restrict__ rowptr,
                                              const int* __restrict__ col,
                                              const float* __restrict__ basein,
                                              float basescale, float invlp1, int write_x,
                                              float* __restrict__ xnew, float* __restrict__ avg, int N) {
    int wave = threadIdx.x >> 6;
    int lane = threadIdx.x & 63;
    int d = blockIdx.x * 4 + wave;
    if (d >= N) return;

    int beg = rowptr[d], end = rowptr[d + 1];
    bool act = lane < (D / 2);

    float2 acc = make_float2(0.f, 0.f);
    if (act) {  // self loop
        unsigned int v = ((const unsigned int*)(y16 + (long)d * YSTRIDE))[lane];
        acc.x = __uint_as_float(v << 16);
        acc.y = __uint_as_float(v & 0xffff0000u);
    }
    for (int base = beg; base < end; base += 64) {
        int m = min(64, end - base);
        int c = (lane < m) ? col[base + lane] : 0;
        for (int j = 0; j < m; j++) {
            int s = __shfl(c, j);
            if (act) {
                unsigned int v = ((const unsigned int*)(y16 + (long)s * YSTRIDE))[lane];
                acc.x += __uint_as_float(v << 16);
                acc.y += __uint_as_float(v & 0xffff0000u);
            }
        }
    }
    float dinv = 1.f / (float)(end - beg + 1);
    acc.x *= dinv;
    acc.y *= dinv;

    float nsq = act ? (acc.x * acc.x + acc.y * acc.y) : 0.f;
    for (int off = 32; off; off >>= 1) nsq += __shfl_xor(nsq, off);
    float scale = invlp1 / fmaxf(sqrtf(nsq), 1e-12f);

    if (act) {
        if (write_x) *(float2*)(xnew + (long)d * D + lane * 2) = acc;
        float2 b = *(const float2*)(basein + (long)d * D + lane * 2);
        float2 o;
        o.x = b.x * basescale + acc.x * scale;
        o.y = b.y * basescale + acc.y * scale;
        *(float2*)(avg + (long)d * D + lane * 2) = o;
    }
}

// ---------------- launcher ----------------

extern "C" void kernel_launch(void* const* d_in, const int* in_sizes, int n_in,
                              void* d_out, int out_size, void* d_ws, size_t ws_size,
                              hipStream_t stream) {
    const float* features = (const float*)d_in[0];
    const float* W        = (const float*)d_in[1];
    const int*   src      = (const int*)d_in[2];
    const int*   dstv     = (const int*)d_in[3];

    int N = in_sizes[0] / D;            // 50000
    int E = in_sizes[2];                // 800000
    int L = in_sizes[1] / (D * D);      // 2
    float invlp1 = 1.f / (float)(L + 1);

    char*  ws  = (char*)d_ws;
    size_t off = 0;
    auto alloc = [&](size_t bytes) -> void* {
        void* p = (void*)(ws + off);
        off += (bytes + 255) & ~(size_t)255;
        return p;
    };
    unsigned short* y16    = (unsigned short*)alloc((size_t)N * YSTRIDE * sizeof(unsigned short));
    float*          xbuf   = (float*)alloc((size_t)N * D * sizeof(float));
    int*            colb   = (int*)alloc((size_t)E * sizeof(int));
    int*            cnt    = (int*)alloc((size_t)N * sizeof(int));
    int*            rowptr = (int*)alloc((size_t)(N + 1) * sizeof(int));
    int*            cur    = (int*)alloc((size_t)N * sizeof(int));
    int             NB     = (N + 255) / 256;
    int*            bsum   = (int*)alloc((size_t)NB * sizeof(int));
    int*            boff   = (int*)alloc((size_t)NB * sizeof(int));

    // CSR build (per call — ws is re-poisoned before every timed launch)
    hipMemsetAsync(cnt, 0, (size_t)N * sizeof(int), stream);
    k_hist<<<(E + 255) / 256, 256, 0, stream>>>(dstv, cnt, E);
    k_blocksum<<<NB, 256, 0, stream>>>(cnt, bsum, N);
    k_scan_bsum<<<1, 256, 0, stream>>>(bsum, boff, NB);
    k_scan_write<<<NB, 256, 0, stream>>>(cnt, boff, rowptr, N, E);
    hipMemcpyAsync(cur, rowptr, (size_t)N * sizeof(int), hipMemcpyDeviceToDevice, stream);
    k_fill<<<(E + 255) / 256, 256, 0, stream>>>(src, dstv, cur, colb, E);

    float* out = (float*)d_out;
    const float* xin = features;
    int nrowtiles = (N + 15) / 16;
    int gemmblocks = (nrowtiles + 3) / 4;
    for (int l = 0; l < L; l++) {
        k_gemm_mfma<<<gemmblocks, 256, 0, stream>>>(xin, W + (size_t)l * D * D, y16, N);
        const float* basein = (l == 0) ? features : out;
        float bscale        = (l == 0) ? invlp1 : 1.f;
        int   write_x       = (l < L - 1) ? 1 : 0;
        k_spmm<<<(N + 3) / 4, 256, 0, stream>>>(y16, rowptr, colb, basein, bscale, invlp1, write_x,
                                                xbuf, out, N);
        xin = xbuf;
    }
}

// Round 4
// 266.468 us; speedup vs baseline: 1.7669x; 1.2483x over previous
//
#include <hip/hip_runtime.h>

#define D 100
#define YSTRIDE 128  // y row stride in bf16 elements (256 B = 64 uints, 2 aligned lines)

typedef __attribute__((ext_vector_type(8))) short bf8v;
typedef __attribute__((ext_vector_type(4))) float f4v;

__device__ inline unsigned short f2bf(float f) {
    unsigned u = __float_as_uint(f);
    return (unsigned short)((u + 0x7fffu + ((u >> 16) & 1u)) >> 16);  // RNE
}
__device__ inline float bflo(unsigned v) { return __uint_as_float(v << 16); }
__device__ inline float bfhi(unsigned v) { return __uint_as_float(v & 0xffff0000u); }

// ---------------- CSR build ----------------

__global__ __launch_bounds__(256) void k_hist(const int* __restrict__ dst, int* __restrict__ cnt, int E) {
    int e = blockIdx.x * 256 + threadIdx.x;
    if (e < E) atomicAdd(&cnt[dst[e]], 1);
}

__global__ __launch_bounds__(256) void k_blocksum(const int* __restrict__ cnt, int* __restrict__ bsum, int n) {
    __shared__ int s[256];
    int i = blockIdx.x * 256 + threadIdx.x;
    s[threadIdx.x] = (i < n) ? cnt[i] : 0;
    __syncthreads();
    for (int off = 128; off; off >>= 1) {
        if (threadIdx.x < off) s[threadIdx.x] += s[threadIdx.x + off];
        __syncthreads();
    }
    if (threadIdx.x == 0) bsum[blockIdx.x] = s[0];
}

__global__ __launch_bounds__(256) void k_scan_bsum(const int* __restrict__ bsum, int* __restrict__ boff, int nb) {
    __shared__ int s[256];
    int v = (threadIdx.x < nb) ? bsum[threadIdx.x] : 0;
    s[threadIdx.x] = v;
    __syncthreads();
    for (int off = 1; off < 256; off <<= 1) {
        int t = (threadIdx.x >= off) ? s[threadIdx.x - off] : 0;
        __syncthreads();
        s[threadIdx.x] += t;
        __syncthreads();
    }
    if (threadIdx.x < nb) boff[threadIdx.x] = s[threadIdx.x] - v;  // exclusive
}

// writes rowptr AND cur (saves a d2d memcpy)
__global__ __launch_bounds__(256) void k_scan_write(const int* __restrict__ cnt, const int* __restrict__ boff,
                                                    int* __restrict__ rowptr, int* __restrict__ cur,
                                                    int n, int E) {
    __shared__ int s[256];
    int i = blockIdx.x * 256 + threadIdx.x;
    int v = (i < n) ? cnt[i] : 0;
    s[threadIdx.x] = v;
    __syncthreads();
    for (int off = 1; off < 256; off <<= 1) {
        int t = (threadIdx.x >= off) ? s[threadIdx.x - off] : 0;
        __syncthreads();
        s[threadIdx.x] += t;
        __syncthreads();
    }
    if (i < n) {
        int rp = boff[blockIdx.x] + s[threadIdx.x] - v;
        rowptr[i] = rp;
        cur[i] = rp;
    }
    if (blockIdx.x == 0 && threadIdx.x == 0) rowptr[n] = E;
}

__global__ __launch_bounds__(256) void k_fill(const int* __restrict__ src, const int* __restrict__ dst,
                                              int* __restrict__ cur, int* __restrict__ col, int E) {
    int e = blockIdx.x * 256 + threadIdx.x;
    if (e >= E) return;
    int d = dst[e];
    int pos = atomicAdd(&cur[d], 1);
    col[pos] = src[e];
}

// ---------------- W pre-pack into MFMA B-fragment bf16 layout ----------------
// out[((l*7+nt)*4+kt)*64 + lane] = 8 bf16: W[l][nt*16+(lane&15)][kt*32+(lane>>4)*8 + j]
__global__ __launch_bounds__(256) void k_wprep(const float* __restrict__ W, unsigned short* __restrict__ P,
                                               int total) {
    int t = blockIdx.x * 256 + threadIdx.x;
    if (t >= total) return;
    int lane = t & 63;
    int r = t >> 6;
    int kt = r & 3;
    int r2 = r >> 2;
    int nt = r2 % 7;
    int l  = r2 / 7;
    int ng = nt * 16 + (lane & 15);
    int k0 = kt * 32 + (lane >> 4) * 8;
    unsigned short u[8];
#pragma unroll
    for (int j = 0; j < 8; j++) {
        int k = k0 + j;
        u[j] = (ng < D && k < D) ? f2bf(W[(long)l * D * D + (long)ng * D + k]) : (unsigned short)0;
    }
    uint4* outp = (uint4*)(P + (long)t * 8);
    uint4 o;
    o.x = (unsigned)u[0] | ((unsigned)u[1] << 16);
    o.y = (unsigned)u[2] | ((unsigned)u[3] << 16);
    o.z = (unsigned)u[4] | ((unsigned)u[5] << 16);
    o.w = (unsigned)u[6] | ((unsigned)u[7] << 16);
    *outp = o;
}

// ---------------- MFMA GEMM: y16 = bf16(x @ W^T) ----------------
// One wave per 16-row tile. B frags prepacked (L1-resident 28 KB).
__global__ __launch_bounds__(256) void k_gemm_mfma(const float* __restrict__ x,
                                                   const unsigned short* __restrict__ P,
                                                   unsigned short* __restrict__ y16, int N) {
    int wave = threadIdx.x >> 6;
    int lane = threadIdx.x & 63;
    int quad = lane >> 4;
    int l16  = lane & 15;
    int rowbase = (blockIdx.x * 4 + wave) * 16;
    if (rowbase >= N) return;

    // ---- A fragments (4 k-steps) from fp32 x ----
    bf8v afrag[4];
    int arow = rowbase + l16;
    if (arow >= N) arow = N - 1;  // rows >= N are discarded at store
    const float* xr = x + (long)arow * D;
#pragma unroll
    for (int kt = 0; kt < 4; kt++) {
        int k0 = kt * 32 + quad * 8;
        union { bf8v v; unsigned short u[8]; } a;
        if (k0 + 8 <= D) {
            float4 p = *(const float4*)(xr + k0);
            float4 q = *(const float4*)(xr + k0 + 4);
            a.u[0] = f2bf(p.x); a.u[1] = f2bf(p.y); a.u[2] = f2bf(p.z); a.u[3] = f2bf(p.w);
            a.u[4] = f2bf(q.x); a.u[5] = f2bf(q.y); a.u[6] = f2bf(q.z); a.u[7] = f2bf(q.w);
        } else {
#pragma unroll
            for (int j = 0; j < 8; j++) a.u[j] = (k0 + j < D) ? f2bf(xr[k0 + j]) : (unsigned short)0;
        }
        afrag[kt] = a.v;
    }

    // ---- MFMA over prepacked B frags ----
    f4v acc[7];
#pragma unroll
    for (int nt = 0; nt < 7; nt++) acc[nt] = (f4v){0.f, 0.f, 0.f, 0.f};

    const uint4* bp = (const uint4*)P;
#pragma unroll
    for (int nt = 0; nt < 7; nt++) {
#pragma unroll
        for (int kt = 0; kt < 4; kt++) {
            union { uint4 u; bf8v v; } b;
            b.u = bp[(nt * 4 + kt) * 64 + lane];
            acc[nt] = __builtin_amdgcn_mfma_f32_16x16x32_bf16(afrag[kt], b.v, acc[nt], 0, 0, 0);
        }
    }

    // ---- store C -> y16 (bf16, YSTRIDE-padded rows) ----
    unsigned short* yr = y16 + (long)rowbase * YSTRIDE;
#pragma unroll
    for (int nt = 0; nt < 7; nt++) {
        int cc = nt * 16 + l16;
        if (cc < D) {
#pragma unroll
            for (int i = 0; i < 4; i++) {
                int rr = quad * 4 + i;
                if (rowbase + rr < N)
                    yr[(long)rr * YSTRIDE + cc] = f2bf(acc[nt][i]);
            }
        }
    }
}

// ---------------- fused SpMM + row-normalize + avg update ----------------
// One wave per node. Scalar loop control (readfirstlane), v_readlane edge
// indices -> saddr loads, 4-wide unroll for memory parallelism.
__global__ __launch_bounds__(256) void k_spmm(const unsigned short* __restrict__ y16,
                                              const int* __restrict__ rowptr,
                                              const int* __restrict__ col,
                                              const float* __restrict__ basein,
                                              float basescale, float invlp1, int write_x,
                                              float* __restrict__ xnew, float* __restrict__ avg, int N) {
    int wave = threadIdx.x >> 6;
    int lane = threadIdx.x & 63;
    int d = blockIdx.x * 4 + wave;
    if (d >= N) return;

    int beg = __builtin_amdgcn_readfirstlane(rowptr[d]);
    int end = __builtin_amdgcn_readfirstlane(rowptr[d + 1]);

    const unsigned int* __restrict__ yb = (const unsigned int*)y16;  // row stride 64 uints

    // self loop (lanes 50..63 read padding — safe, discarded)
    unsigned sv = yb[(long)d * 64 + lane];
    float ax = bflo(sv), ay = bfhi(sv);

    for (int base = beg; base < end; base += 64) {
        int m = end - base;
        if (m > 64) m = 64;
        int c = col[base + lane];  // lanes >= m load garbage; never consumed
        int j = 0;
        for (; j + 4 <= m; j += 4) {
            int s0 = __builtin_amdgcn_readlane(c, j);
            int s1 = __builtin_amdgcn_readlane(c, j + 1);
            int s2 = __builtin_amdgcn_readlane(c, j + 2);
            int s3 = __builtin_amdgcn_readlane(c, j + 3);
            unsigned v0 = yb[(long)s0 * 64 + lane];
            unsigned v1 = yb[(long)s1 * 64 + lane];
            unsigned v2 = yb[(long)s2 * 64 + lane];
            unsigned v3 = yb[(long)s3 * 64 + lane];
            ax += (bflo(v0) + bflo(v1)) + (bflo(v2) + bflo(v3));
            ay += (bfhi(v0) + bfhi(v1)) + (bfhi(v2) + bfhi(v3));
        }
        for (; j < m; j++) {
            int s = __builtin_amdgcn_readlane(c, j);
            unsigned v = yb[(long)s * 64 + lane];
            ax += bflo(v);
            ay += bfhi(v);
        }
    }

    float dinv = 1.f / (float)(end - beg + 1);
    ax *= dinv;
    ay *= dinv;

    bool act = lane < (D / 2);
    float nsq = act ? (ax * ax + ay * ay) : 0.f;
    for (int off = 32; off; off >>= 1) nsq += __shfl_xor(nsq, off);
    float scale = invlp1 / fmaxf(sqrtf(nsq), 1e-12f);

    if (act) {
        if (write_x) *(float2*)(xnew + (long)d * D + lane * 2) = make_float2(ax, ay);
        float2 b = *(const float2*)(basein + (long)d * D + lane * 2);
        float2 o;
        o.x = b.x * basescale + ax * scale;
        o.y = b.y * basescale + ay * scale;
        *(float2*)(avg + (long)d * D + lane * 2) = o;
    }
}

// ---------------- launcher ----------------

extern "C" void kernel_launch(void* const* d_in, const int* in_sizes, int n_in,
                              void* d_out, int out_size, void* d_ws, size_t ws_size,
                              hipStream_t stream) {
    const float* features = (const float*)d_in[0];
    const float* W        = (const float*)d_in[1];
    const int*   src      = (const int*)d_in[2];
    const int*   dstv     = (const int*)d_in[3];

    int N = in_sizes[0] / D;            // 50000
    int E = in_sizes[2];                // 800000
    int L = in_sizes[1] / (D * D);      // 2
    float invlp1 = 1.f / (float)(L + 1);

    char*  ws  = (char*)d_ws;
    size_t off = 0;
    auto alloc = [&](size_t bytes) -> void* {
        void* p = (void*)(ws + off);
        off += (bytes + 255) & ~(size_t)255;
        return p;
    };
    unsigned short* y16    = (unsigned short*)alloc((size_t)N * YSTRIDE * sizeof(unsigned short));
    float*          xbuf   = (float*)alloc((size_t)N * D * sizeof(float));
    unsigned short* wpack  = (unsigned short*)alloc((size_t)L * 7 * 4 * 64 * 8 * sizeof(unsigned short));
    int*            colb   = (int*)alloc((size_t)E * sizeof(int));
    int*            cnt    = (int*)alloc((size_t)N * sizeof(int));
    int*            rowptr = (int*)alloc((size_t)(N + 1) * sizeof(int));
    int*            cur    = (int*)alloc((size_t)N * sizeof(int));
    int             NB     = (N + 255) / 256;
    int*            bsum   = (int*)alloc((size_t)NB * sizeof(int));
    int*            boff   = (int*)alloc((size_t)NB * sizeof(int));

    // CSR build (per call — ws is re-poisoned before every timed launch)
    hipMemsetAsync(cnt, 0, (size_t)N * sizeof(int), stream);
    k_hist<<<(E + 255) / 256, 256, 0, stream>>>(dstv, cnt, E);
    k_blocksum<<<NB, 256, 0, stream>>>(cnt, bsum, N);
    k_scan_bsum<<<1, 256, 0, stream>>>(bsum, boff, NB);
    k_scan_write<<<NB, 256, 0, stream>>>(cnt, boff, rowptr, cur, N, E);
    k_fill<<<(E + 255) / 256, 256, 0, stream>>>(src, dstv, cur, colb, E);
    int wtot = L * 7 * 4 * 64;
    k_wprep<<<(wtot + 255) / 256, 256, 0, stream>>>(W, wpack, wtot);

    float* out = (float*)d_out;
    const float* xin = features;
    int nrowtiles  = (N + 15) / 16;
    int gemmblocks = (nrowtiles + 3) / 4;
    for (int l = 0; l < L; l++) {
        k_gemm_mfma<<<gemmblocks, 256, 0, stream>>>(xin, wpack + (size_t)l * 7 * 4 * 64 * 8, y16, N);
        const float* basein = (l == 0) ? features : out;
        float bscale        = (l == 0) ? invlp1 : 1.f;
        int   write_x       = (l < L - 1) ? 1 : 0;
        k_spmm<<<(N + 3) / 4, 256, 0, stream>>>(y16, rowptr, colb, basein, bscale, invlp1, write_x,
                                                xbuf, out, N);
        xin = xbuf;
    }
}

// Round 5
// 230.767 us; speedup vs baseline: 2.0403x; 1.1547x over previous
//
#include <hip/hip_runtime.h>

#define D 100
#define YSTRIDE 128   // y row stride in bf16 elements (256 B = 64 uints)
#define BSHIFT 7      // 128 dst nodes per bucket
#define BSIZE 128
#define BMASK 127
#define NBKMAX 512    // supports N <= 65536
#define EPB 8192      // edges per block in bucket passes
#define DCAP 4096     // per-bucket edge staging capacity in phase D

typedef __attribute__((ext_vector_type(8))) short bf8v;
typedef __attribute__((ext_vector_type(4))) float f4v;

__device__ inline unsigned short f2bf(float f) {
    unsigned u = __float_as_uint(f);
    return (unsigned short)((u + 0x7fffu + ((u >> 16) & 1u)) >> 16);  // RNE
}
__device__ inline float bflo(unsigned v) { return __uint_as_float(v << 16); }
__device__ inline float bfhi(unsigned v) { return __uint_as_float(v & 0xffff0000u); }

// exclusive scan of a[0..512) in LDS, t[256] scratch; all 256 threads participate
__device__ inline void scan512_excl(int* a, int* t, int tid) {
    int v0 = a[2 * tid], v1 = a[2 * tid + 1];
    t[tid] = v0 + v1;
    __syncthreads();
    for (int off = 1; off < 256; off <<= 1) {
        int u = (tid >= off) ? t[tid - off] : 0;
        __syncthreads();
        t[tid] += u;
        __syncthreads();
    }
    int base = (tid ? t[tid - 1] : 0);
    a[2 * tid]     = base;
    a[2 * tid + 1] = base + v0;
    __syncthreads();
}

// ---------------- Phase A: bucket histogram (LDS-staged) ----------------
__global__ __launch_bounds__(256) void k_bucketA(const int* __restrict__ dst,
                                                 int* __restrict__ bucket_cnt, int E, int nbk) {
    __shared__ int lhist[NBKMAX];
    int tid = threadIdx.x;
    int base = blockIdx.x * EPB;
    int count = min(EPB, E - base);
    for (int i = tid; i < NBKMAX; i += 256) lhist[i] = 0;
    __syncthreads();
    for (int i = tid; i < count; i += 256) atomicAdd(&lhist[dst[base + i] >> BSHIFT], 1);
    __syncthreads();
    for (int b = tid; b < nbk; b += 256)
        if (lhist[b]) atomicAdd(&bucket_cnt[b], lhist[b]);
}

// ---------------- Phase B: scan bucket counts -> offsets + cursors ----------------
__global__ __launch_bounds__(256) void k_scanB(const int* __restrict__ bucket_cnt,
                                               int* __restrict__ bucket_off,
                                               int* __restrict__ bucket_cur, int nbk, int E) {
    __shared__ int a[NBKMAX], t[256];
    int tid = threadIdx.x;
    a[tid]       = (tid < nbk) ? bucket_cnt[tid] : 0;
    a[tid + 256] = (tid + 256 < nbk) ? bucket_cnt[tid + 256] : 0;
    __syncthreads();
    scan512_excl(a, t, tid);
    if (tid < nbk)       { bucket_off[tid] = a[tid];             bucket_cur[tid] = a[tid]; }
    if (tid + 256 < nbk) { bucket_off[tid + 256] = a[tid + 256]; bucket_cur[tid + 256] = a[tid + 256]; }
    if (tid == 0) bucket_off[nbk] = E;
}

// ---------------- Phase C: bucketed edge dump, coalesced writes ----------------
// ebuf entry: (dst & 127) << 16 | src   (requires N <= 65536)
__global__ __launch_bounds__(256) void k_bucketC(const int* __restrict__ src,
                                                 const int* __restrict__ dst,
                                                 int* __restrict__ bucket_cur,
                                                 unsigned* __restrict__ ebuf, int E, int nbk) {
    __shared__ int lhist[NBKMAX], lstart[NBKMAX], runS[NBKMAX], t[256];
    __shared__ unsigned stage[EPB];
    int tid = threadIdx.x;
    int base = blockIdx.x * EPB;
    int count = min(EPB, E - base);

    for (int i = tid; i < NBKMAX; i += 256) lhist[i] = 0;
    __syncthreads();
    for (int i = tid; i < count; i += 256) atomicAdd(&lhist[dst[base + i] >> BSHIFT], 1);
    __syncthreads();
    for (int i = tid; i < NBKMAX; i += 256) lstart[i] = lhist[i];
    __syncthreads();
    scan512_excl(lstart, t, tid);
    // reserve global runs
    for (int b = tid; b < nbk; b += 256) {
        int c = lhist[b];
        runS[b] = c ? atomicAdd(&bucket_cur[b], c) : 0;
    }
    __syncthreads();
    // reset lhist as rank cursor
    for (int i = tid; i < NBKMAX; i += 256) lhist[i] = 0;
    __syncthreads();
    for (int i = tid; i < count; i += 256) {
        int dv = dst[base + i];
        int sv = src[base + i];
        int b = dv >> BSHIFT;
        int r = atomicAdd(&lhist[b], 1);
        stage[lstart[b] + r] = ((unsigned)(dv & BMASK) << 16) | (unsigned)sv;
    }
    __syncthreads();
    // flush runs, wave per bucket round-robin (coalesced)
    int wave = tid >> 6, lane = tid & 63;
    for (int b = wave; b < nbk; b += 4) {
        int c = lhist[b], ls = lstart[b], rs = runS[b];
        for (int j = lane; j < c; j += 64) ebuf[rs + j] = stage[ls + j];
    }
}

// ---------------- Phase D: per-bucket CSR finalize (coalesced) ----------------
__global__ __launch_bounds__(256) void k_bucketD(const unsigned* __restrict__ ebuf,
                                                 const int* __restrict__ bucket_off,
                                                 int* __restrict__ col, int* __restrict__ rowptr,
                                                 int N, int nbk, int E) {
    __shared__ int lh[BSIZE], ls[BSIZE];
    __shared__ int colStage[DCAP];
    int b = blockIdx.x;
    int tid = threadIdx.x;
    int beg = bucket_off[b], end = bucket_off[b + 1];
    int cnt = end - beg;

    if (tid < BSIZE) lh[tid] = 0;
    __syncthreads();
    for (int i = tid; i < cnt; i += 256) atomicAdd(&lh[ebuf[beg + i] >> 16], 1);
    __syncthreads();
    if (tid < BSIZE) ls[tid] = lh[tid];
    __syncthreads();
    for (int off = 1; off < BSIZE; off <<= 1) {
        int v = (tid >= off && tid < BSIZE) ? ls[tid - off] : 0;
        __syncthreads();
        if (tid < BSIZE) ls[tid] += v;
        __syncthreads();
    }
    // inclusive -> exclusive
    if (tid < BSIZE) ls[tid] -= lh[tid];
    __syncthreads();
    // rowptr
    int d0 = b * BSIZE;
    if (tid < BSIZE && d0 + tid < N) rowptr[d0 + tid] = beg + ls[tid];
    if (b == nbk - 1 && tid == 0) rowptr[N] = E;
    // reset lh as cursor
    if (tid < BSIZE) lh[tid] = 0;
    __syncthreads();
    if (cnt <= DCAP) {
        for (int i = tid; i < cnt; i += 256) {
            unsigned p = ebuf[beg + i];
            int r = p >> 16, s = (int)(p & 0xffffu);
            int k = atomicAdd(&lh[r], 1);
            colStage[ls[r] + k] = s;
        }
        __syncthreads();
        for (int i = tid; i < cnt; i += 256) col[beg + i] = colStage[i];
    } else {  // fallback (statistically unreachable for uniform graphs)
        for (int i = tid; i < cnt; i += 256) {
            unsigned p = ebuf[beg + i];
            int r = p >> 16, s = (int)(p & 0xffffu);
            int k = atomicAdd(&lh[r], 1);
            col[beg + ls[r] + k] = s;
        }
    }
}

// ---------------- W pre-pack into MFMA B-fragment bf16 layout ----------------
__global__ __launch_bounds__(256) void k_wprep(const float* __restrict__ W, unsigned short* __restrict__ P,
                                               int total) {
    int t = blockIdx.x * 256 + threadIdx.x;
    if (t >= total) return;
    int lane = t & 63;
    int r = t >> 6;
    int kt = r & 3;
    int r2 = r >> 2;
    int nt = r2 % 7;
    int l  = r2 / 7;
    int ng = nt * 16 + (lane & 15);
    int k0 = kt * 32 + (lane >> 4) * 8;
    unsigned short u[8];
#pragma unroll
    for (int j = 0; j < 8; j++) {
        int k = k0 + j;
        u[j] = (ng < D && k < D) ? f2bf(W[(long)l * D * D + (long)ng * D + k]) : (unsigned short)0;
    }
    uint4* outp = (uint4*)(P + (long)t * 8);
    uint4 o;
    o.x = (unsigned)u[0] | ((unsigned)u[1] << 16);
    o.y = (unsigned)u[2] | ((unsigned)u[3] << 16);
    o.z = (unsigned)u[4] | ((unsigned)u[5] << 16);
    o.w = (unsigned)u[6] | ((unsigned)u[7] << 16);
    *outp = o;
}

// ---------------- MFMA GEMM: y16 = bf16(x @ W^T) ----------------
__global__ __launch_bounds__(256) void k_gemm_mfma(const float* __restrict__ x,
                                                   const unsigned short* __restrict__ P,
                                                   unsigned short* __restrict__ y16, int N) {
    int wave = threadIdx.x >> 6;
    int lane = threadIdx.x & 63;
    int quad = lane >> 4;
    int l16  = lane & 15;
    int rowbase = (blockIdx.x * 4 + wave) * 16;
    if (rowbase >= N) return;

    bf8v afrag[4];
    int arow = rowbase + l16;
    if (arow >= N) arow = N - 1;
    const float* xr = x + (long)arow * D;
#pragma unroll
    for (int kt = 0; kt < 4; kt++) {
        int k0 = kt * 32 + quad * 8;
        union { bf8v v; unsigned short u[8]; } a;
        if (k0 + 8 <= D) {
            float4 p = *(const float4*)(xr + k0);
            float4 q = *(const float4*)(xr + k0 + 4);
            a.u[0] = f2bf(p.x); a.u[1] = f2bf(p.y); a.u[2] = f2bf(p.z); a.u[3] = f2bf(p.w);
            a.u[4] = f2bf(q.x); a.u[5] = f2bf(q.y); a.u[6] = f2bf(q.z); a.u[7] = f2bf(q.w);
        } else {
#pragma unroll
            for (int j = 0; j < 8; j++) a.u[j] = (k0 + j < D) ? f2bf(xr[k0 + j]) : (unsigned short)0;
        }
        afrag[kt] = a.v;
    }

    f4v acc[7];
#pragma unroll
    for (int nt = 0; nt < 7; nt++) acc[nt] = (f4v){0.f, 0.f, 0.f, 0.f};

    const uint4* bp = (const uint4*)P;
#pragma unroll
    for (int nt = 0; nt < 7; nt++) {
#pragma unroll
        for (int kt = 0; kt < 4; kt++) {
            union { uint4 u; bf8v v; } b;
            b.u = bp[(nt * 4 + kt) * 64 + lane];
            acc[nt] = __builtin_amdgcn_mfma_f32_16x16x32_bf16(afrag[kt], b.v, acc[nt], 0, 0, 0);
        }
    }

    unsigned short* yr = y16 + (long)rowbase * YSTRIDE;
#pragma unroll
    for (int nt = 0; nt < 7; nt++) {
        int cc = nt * 16 + l16;
        if (cc < D) {
#pragma unroll
            for (int i = 0; i < 4; i++) {
                int rr = quad * 4 + i;
                if (rowbase + rr < N)
                    yr[(long)rr * YSTRIDE + cc] = f2bf(acc[nt][i]);
            }
        }
    }
}

// ---------------- fused SpMM + row-normalize + avg update ----------------
__global__ __launch_bounds__(256) void k_spmm(const unsigned short* __restrict__ y16,
                                              const int* __restrict__ rowptr,
                                              const int* __restrict__ col,
                                              const float* __restrict__ basein,
                                              float basescale, float invlp1, int write_x,
                                              float* __restrict__ xnew, float* __restrict__ avg, int N) {
    int wave = threadIdx.x >> 6;
    int lane = threadIdx.x & 63;
    int d = blockIdx.x * 4 + wave;
    if (d >= N) return;

    int beg = __builtin_amdgcn_readfirstlane(rowptr[d]);
    int end = __builtin_amdgcn_readfirstlane(rowptr[d + 1]);

    const unsigned int* __restrict__ yb = (const unsigned int*)y16;  // row stride 64 uints

    unsigned sv = yb[(long)d * 64 + lane];
    float ax = bflo(sv), ay = bfhi(sv);

    for (int base = beg; base < end; base += 64) {
        int m = end - base;
        if (m > 64) m = 64;
        int c = col[base + lane];
        int j = 0;
        for (; j + 4 <= m; j += 4) {
            int s0 = __builtin_amdgcn_readlane(c, j);
            int s1 = __builtin_amdgcn_readlane(c, j + 1);
            int s2 = __builtin_amdgcn_readlane(c, j + 2);
            int s3 = __builtin_amdgcn_readlane(c, j + 3);
            unsigned v0 = yb[(long)s0 * 64 + lane];
            unsigned v1 = yb[(long)s1 * 64 + lane];
            unsigned v2 = yb[(long)s2 * 64 + lane];
            unsigned v3 = yb[(long)s3 * 64 + lane];
            ax += (bflo(v0) + bflo(v1)) + (bflo(v2) + bflo(v3));
            ay += (bfhi(v0) + bfhi(v1)) + (bfhi(v2) + bfhi(v3));
        }
        for (; j < m; j++) {
            int s = __builtin_amdgcn_readlane(c, j);
            unsigned v = yb[(long)s * 64 + lane];
            ax += bflo(v);
            ay += bfhi(v);
        }
    }

    float dinv = 1.f / (float)(end - beg + 1);
    ax *= dinv;
    ay *= dinv;

    bool act = lane < (D / 2);
    float nsq = act ? (ax * ax + ay * ay) : 0.f;
    for (int off = 32; off; off >>= 1) nsq += __shfl_xor(nsq, off);
    float scale = invlp1 / fmaxf(sqrtf(nsq), 1e-12f);

    if (act) {
        if (write_x) *(float2*)(xnew + (long)d * D + lane * 2) = make_float2(ax, ay);
        float2 b = *(const float2*)(basein + (long)d * D + lane * 2);
        float2 o;
        o.x = b.x * basescale + ax * scale;
        o.y = b.y * basescale + ay * scale;
        *(float2*)(avg + (long)d * D + lane * 2) = o;
    }
}

// ---------------- launcher ----------------

extern "C" void kernel_launch(void* const* d_in, const int* in_sizes, int n_in,
                              void* d_out, int out_size, void* d_ws, size_t ws_size,
                              hipStream_t stream) {
    const float* features = (const float*)d_in[0];
    const float* W        = (const float*)d_in[1];
    const int*   src      = (const int*)d_in[2];
    const int*   dstv     = (const int*)d_in[3];

    int N = in_sizes[0] / D;            // 50000
    int E = in_sizes[2];                // 800000
    int L = in_sizes[1] / (D * D);      // 2
    float invlp1 = 1.f / (float)(L + 1);
    int NBK = (N + BSIZE - 1) >> BSHIFT;

    char*  ws  = (char*)d_ws;
    size_t off = 0;
    auto alloc = [&](size_t bytes) -> void* {
        void* p = (void*)(ws + off);
        off += (bytes + 255) & ~(size_t)255;
        return p;
    };
    unsigned short* y16    = (unsigned short*)alloc((size_t)N * YSTRIDE * sizeof(unsigned short));
    float*          xbuf   = (float*)alloc((size_t)N * D * sizeof(float));
    unsigned short* wpack  = (unsigned short*)alloc((size_t)L * 7 * 4 * 64 * 8 * sizeof(unsigned short));
    unsigned*       ebuf   = (unsigned*)alloc((size_t)E * sizeof(unsigned));
    int*            colb   = (int*)alloc((size_t)E * sizeof(int));
    int*            rowptr = (int*)alloc((size_t)(N + 1) * sizeof(int));
    int*            bcnt   = (int*)alloc((size_t)NBKMAX * sizeof(int));
    int*            boff   = (int*)alloc((size_t)(NBKMAX + 1) * sizeof(int));
    int*            bcur   = (int*)alloc((size_t)NBKMAX * sizeof(int));

    int nebk = (E + EPB - 1) / EPB;
    hipMemsetAsync(bcnt, 0, (size_t)NBK * sizeof(int), stream);
    k_bucketA<<<nebk, 256, 0, stream>>>(dstv, bcnt, E, NBK);
    k_scanB<<<1, 256, 0, stream>>>(bcnt, boff, bcur, NBK, E);
    k_bucketC<<<nebk, 256, 0, stream>>>(src, dstv, bcur, ebuf, E, NBK);
    k_bucketD<<<NBK, 256, 0, stream>>>(ebuf, boff, colb, rowptr, N, NBK, E);
    int wtot = L * 7 * 4 * 64;
    k_wprep<<<(wtot + 255) / 256, 256, 0, stream>>>(W, wpack, wtot);

    float* out = (float*)d_out;
    const float* xin = features;
    int nrowtiles  = (N + 15) / 16;
    int gemmblocks = (nrowtiles + 3) / 4;
    for (int l = 0; l < L; l++) {
        k_gemm_mfma<<<gemmblocks, 256, 0, stream>>>(xin, wpack + (size_t)l * 7 * 4 * 64 * 8, y16, N);
        const float* basein = (l == 0) ? features : out;
        float bscale        = (l == 0) ? invlp1 : 1.f;
        int   write_x       = (l < L - 1) ? 1 : 0;
        k_spmm<<<(N + 3) / 4, 256, 0, stream>>>(y16, rowptr, colb, basein, bscale, invlp1, write_x,
                                                xbuf, out, N);
        xin = xbuf;
    }
}

// Round 6
// 226.007 us; speedup vs baseline: 2.0833x; 1.0211x over previous
//
#include <hip/hip_runtime.h>

#define D 100
#define YSTRIDE 128   // y row stride in bf16 elements (256 B = 64 uints)
#define BSHIFT 7      // 128 dst nodes per bucket
#define BSIZE 128
#define BMASK 127
#define NBKMAX 512    // supports N <= 65536
#define EPB 2048      // edges per block in bucket passes
#define DCAP 4096     // per-bucket edge staging capacity in phase D

typedef __attribute__((ext_vector_type(8))) short bf8v;
typedef __attribute__((ext_vector_type(4))) float f4v;

__device__ inline unsigned short f2bf(float f) {
    unsigned u = __float_as_uint(f);
    return (unsigned short)((u + 0x7fffu + ((u >> 16) & 1u)) >> 16);  // RNE
}
__device__ inline float bflo(unsigned v) { return __uint_as_float(v << 16); }
__device__ inline float bfhi(unsigned v) { return __uint_as_float(v & 0xffff0000u); }

// exclusive scan of a[0..512) in LDS, t[256] scratch; 256 threads
__device__ inline void scan512_excl(int* a, int* t, int tid) {
    int v0 = a[2 * tid], v1 = a[2 * tid + 1];
    t[tid] = v0 + v1;
    __syncthreads();
    for (int off = 1; off < 256; off <<= 1) {
        int u = (tid >= off) ? t[tid - off] : 0;
        __syncthreads();
        t[tid] += u;
        __syncthreads();
    }
    int base = (tid ? t[tid - 1] : 0);
    a[2 * tid]     = base;
    a[2 * tid + 1] = base + v0;
    __syncthreads();
}

// ---------------- init: zero bucket counters + prepack W ----------------
// wprep: P[((l*7+nt)*4+kt)*64+lane] = 8 bf16 of W[l][nt*16+(lane&15)][kt*32+(lane>>4)*8+j]
__global__ __launch_bounds__(256) void k_init(const float* __restrict__ W, unsigned short* __restrict__ P,
                                              int* __restrict__ bcnt, int wtot) {
    int t = blockIdx.x * 256 + threadIdx.x;
    if (t < NBKMAX) bcnt[t] = 0;
    if (t >= wtot) return;
    int lane = t & 63;
    int r = t >> 6;
    int kt = r & 3;
    int r2 = r >> 2;
    int nt = r2 % 7;
    int l  = r2 / 7;
    int ng = nt * 16 + (lane & 15);
    int k0 = kt * 32 + (lane >> 4) * 8;
    unsigned short u[8];
#pragma unroll
    for (int j = 0; j < 8; j++) {
        int k = k0 + j;
        u[j] = (ng < D && k < D) ? f2bf(W[(long)l * D * D + (long)ng * D + k]) : (unsigned short)0;
    }
    uint4 o;
    o.x = (unsigned)u[0] | ((unsigned)u[1] << 16);
    o.y = (unsigned)u[2] | ((unsigned)u[3] << 16);
    o.z = (unsigned)u[4] | ((unsigned)u[5] << 16);
    o.w = (unsigned)u[6] | ((unsigned)u[7] << 16);
    *(uint4*)(P + (long)t * 8) = o;
}

// ---------------- Phase A: bucket histogram (LDS-staged) ----------------
__global__ __launch_bounds__(256) void k_bucketA(const int* __restrict__ dst,
                                                 int* __restrict__ bucket_cnt, int E, int nbk) {
    __shared__ int lhist[NBKMAX];
    int tid = threadIdx.x;
    int base = blockIdx.x * EPB;
    int count = min(EPB, E - base);
    for (int i = tid; i < NBKMAX; i += 256) lhist[i] = 0;
    __syncthreads();
    for (int i = tid; i < count; i += 256) atomicAdd(&lhist[dst[base + i] >> BSHIFT], 1);
    __syncthreads();
    for (int b = tid; b < nbk; b += 256)
        if (lhist[b]) atomicAdd(&bucket_cnt[b], lhist[b]);
}

// ---------------- Phase B: scan bucket counts -> offsets + cursors ----------------
__global__ __launch_bounds__(256) void k_scanB(const int* __restrict__ bucket_cnt,
                                               int* __restrict__ bucket_off,
                                               int* __restrict__ bucket_cur, int nbk, int E) {
    __shared__ int a[NBKMAX], t[256];
    int tid = threadIdx.x;
    a[tid]       = (tid < nbk) ? bucket_cnt[tid] : 0;
    a[tid + 256] = (tid + 256 < nbk) ? bucket_cnt[tid + 256] : 0;
    __syncthreads();
    scan512_excl(a, t, tid);
    if (tid < nbk)       { bucket_off[tid] = a[tid];             bucket_cur[tid] = a[tid]; }
    if (tid + 256 < nbk) { bucket_off[tid + 256] = a[tid + 256]; bucket_cur[tid + 256] = a[tid + 256]; }
    if (tid == 0) bucket_off[nbk] = E;
}

// ---------------- Phase C: bucketed edge dump, coalesced writes ----------------
// ebuf entry: (dst & 127) << 16 | src   (requires N <= 65536)
__global__ __launch_bounds__(256) void k_bucketC(const int* __restrict__ src,
                                                 const int* __restrict__ dst,
                                                 int* __restrict__ bucket_cur,
                                                 unsigned* __restrict__ ebuf, int E, int nbk) {
    __shared__ int lhist[NBKMAX], lstart[NBKMAX], runS[NBKMAX], t[256];
    __shared__ unsigned stage[EPB];
    int tid = threadIdx.x;
    int base = blockIdx.x * EPB;
    int count = min(EPB, E - base);

    for (int i = tid; i < NBKMAX; i += 256) lhist[i] = 0;
    __syncthreads();
    for (int i = tid; i < count; i += 256) atomicAdd(&lhist[dst[base + i] >> BSHIFT], 1);
    __syncthreads();
    for (int i = tid; i < NBKMAX; i += 256) lstart[i] = lhist[i];
    __syncthreads();
    scan512_excl(lstart, t, tid);
    for (int b = tid; b < nbk; b += 256) {
        int c = lhist[b];
        runS[b] = c ? atomicAdd(&bucket_cur[b], c) : 0;
    }
    __syncthreads();
    for (int i = tid; i < NBKMAX; i += 256) lhist[i] = 0;
    __syncthreads();
    for (int i = tid; i < count; i += 256) {
        int dv = dst[base + i];
        int sv = src[base + i];
        int b = dv >> BSHIFT;
        int r = atomicAdd(&lhist[b], 1);
        stage[lstart[b] + r] = ((unsigned)(dv & BMASK) << 16) | (unsigned)sv;
    }
    __syncthreads();
    int wave = tid >> 6, lane = tid & 63;
    for (int b = wave; b < nbk; b += 4) {
        int c = lhist[b], ls = lstart[b], rs = runS[b];
        for (int j = lane; j < c; j += 64) ebuf[rs + j] = stage[ls + j];
    }
}

// ---------------- Phase D: per-bucket CSR finalize (coalesced) ----------------
__global__ __launch_bounds__(256) void k_bucketD(const unsigned* __restrict__ ebuf,
                                                 const int* __restrict__ bucket_off,
                                                 int* __restrict__ col, int* __restrict__ rowptr,
                                                 int N, int nbk, int E) {
    __shared__ int lh[BSIZE], ls[BSIZE];
    __shared__ int colStage[DCAP];
    int b = blockIdx.x;
    int tid = threadIdx.x;
    int beg = bucket_off[b], end = bucket_off[b + 1];
    int cnt = end - beg;

    if (tid < BSIZE) lh[tid] = 0;
    __syncthreads();
    for (int i = tid; i < cnt; i += 256) atomicAdd(&lh[ebuf[beg + i] >> 16], 1);
    __syncthreads();
    if (tid < BSIZE) ls[tid] = lh[tid];
    __syncthreads();
    for (int off = 1; off < BSIZE; off <<= 1) {
        int v = (tid >= off && tid < BSIZE) ? ls[tid - off] : 0;
        __syncthreads();
        if (tid < BSIZE) ls[tid] += v;
        __syncthreads();
    }
    if (tid < BSIZE) ls[tid] -= lh[tid];
    __syncthreads();
    int d0 = b * BSIZE;
    if (tid < BSIZE && d0 + tid < N) rowptr[d0 + tid] = beg + ls[tid];
    if (b == nbk - 1 && tid == 0) rowptr[N] = E;
    if (tid < BSIZE) lh[tid] = 0;
    __syncthreads();
    if (cnt <= DCAP) {
        for (int i = tid; i < cnt; i += 256) {
            unsigned p = ebuf[beg + i];
            int r = p >> 16, s = (int)(p & 0xffffu);
            int k = atomicAdd(&lh[r], 1);
            colStage[ls[r] + k] = s;
        }
        __syncthreads();
        for (int i = tid; i < cnt; i += 256) col[beg + i] = colStage[i];
    } else {
        for (int i = tid; i < cnt; i += 256) {
            unsigned p = ebuf[beg + i];
            int r = p >> 16, s = (int)(p & 0xffffu);
            int k = atomicAdd(&lh[r], 1);
            col[beg + ls[r] + k] = s;
        }
    }
}

// ---------------- MFMA GEMM core (shared via macro body) ----------------
// A frag: A[m=lane&15][k=quad*8+j]; B prepacked; C[row=quad*4+i][col=lane&15]
#define GEMM_BODY(LOAD_AFRAG)                                                      \
    int wave = threadIdx.x >> 6;                                                   \
    int lane = threadIdx.x & 63;                                                   \
    int quad = lane >> 4;                                                          \
    int l16  = lane & 15;                                                          \
    int rowbase = (blockIdx.x * 4 + wave) * 16;                                    \
    if (rowbase >= N) return;                                                      \
    int arow = rowbase + l16;                                                      \
    if (arow >= N) arow = N - 1;                                                   \
    bf8v afrag[4];                                                                 \
    LOAD_AFRAG                                                                     \
    f4v acc[7];                                                                    \
    _Pragma("unroll") for (int nt = 0; nt < 7; nt++) acc[nt] = (f4v){0.f,0.f,0.f,0.f}; \
    const uint4* bp = (const uint4*)P;                                             \
    _Pragma("unroll") for (int nt = 0; nt < 7; nt++) {                             \
        _Pragma("unroll") for (int kt = 0; kt < 4; kt++) {                         \
            union { uint4 u; bf8v v; } b;                                          \
            b.u = bp[(nt * 4 + kt) * 64 + lane];                                   \
            acc[nt] = __builtin_amdgcn_mfma_f32_16x16x32_bf16(afrag[kt], b.v, acc[nt], 0, 0, 0); \
        }                                                                          \
    }                                                                              \
    unsigned short* yr = y16 + (long)rowbase * YSTRIDE;                            \
    _Pragma("unroll") for (int nt = 0; nt < 7; nt++) {                             \
        int cc = nt * 16 + l16;                                                    \
        if (cc < D) {                                                              \
            _Pragma("unroll") for (int i = 0; i < 4; i++) {                        \
                int rr = quad * 4 + i;                                             \
                if (rowbase + rr < N)                                              \
                    yr[(long)rr * YSTRIDE + cc] = f2bf(acc[nt][i]);                \
            }                                                                      \
        }                                                                          \
    }

__global__ __launch_bounds__(256) void k_gemm_f32(const float* __restrict__ x,
                                                  const unsigned short* __restrict__ P,
                                                  unsigned short* __restrict__ y16, int N) {
    GEMM_BODY({
        const float* xr = x + (long)arow * D;
        _Pragma("unroll") for (int kt = 0; kt < 4; kt++) {
            int k0 = kt * 32 + quad * 8;
            union { bf8v v; unsigned short u[8]; } a;
            if (k0 + 8 <= D) {
                float4 p = *(const float4*)(xr + k0);
                float4 q = *(const float4*)(xr + k0 + 4);
                a.u[0]=f2bf(p.x); a.u[1]=f2bf(p.y); a.u[2]=f2bf(p.z); a.u[3]=f2bf(p.w);
                a.u[4]=f2bf(q.x); a.u[5]=f2bf(q.y); a.u[6]=f2bf(q.z); a.u[7]=f2bf(q.w);
            } else {
                _Pragma("unroll") for (int j = 0; j < 8; j++)
                    a.u[j] = (k0 + j < D) ? f2bf(xr[k0 + j]) : (unsigned short)0;
            }
            afrag[kt] = a.v;
        }
    })
}

// x16 rows are YSTRIDE bf16 with pads zeroed -> direct dwordx4 A-frag loads
__global__ __launch_bounds__(256) void k_gemm_bf16(const unsigned short* __restrict__ x16,
                                                   const unsigned short* __restrict__ P,
                                                   unsigned short* __restrict__ y16, int N) {
    GEMM_BODY({
        const unsigned short* xr = x16 + (long)arow * YSTRIDE;
        _Pragma("unroll") for (int kt = 0; kt < 4; kt++) {
            int k0 = kt * 32 + quad * 8;
            union { bf8v v; uint4 u; } a;
            a.u = *(const uint4*)(xr + k0);
            afrag[kt] = a.v;
        }
    })
}

// ---------------- fused SpMM + row-normalize + avg update ----------------
// Two nodes per wave; combined edge stream [b0,e1) with wave-uniform 0/1
// routing weights; 8-deep gather pipeline via v_readlane saddr loads.
__global__ __launch_bounds__(256) void k_spmm(const unsigned short* __restrict__ y16,
                                              const int* __restrict__ rowptr,
                                              const int* __restrict__ col,
                                              const float* __restrict__ basein,
                                              float basescale, float invlp1, int write_x,
                                              unsigned* __restrict__ xnew16,
                                              float* __restrict__ avg, int N) {
    int wave = threadIdx.x >> 6;
    int lane = threadIdx.x & 63;
    int d0 = (blockIdx.x * 4 + wave) * 2;
    if (d0 >= N) return;
    int d1 = d0 + 1;
    bool has1 = d1 < N;

    int b0 = __builtin_amdgcn_readfirstlane(rowptr[d0]);
    int e0 = __builtin_amdgcn_readfirstlane(rowptr[d0 + 1]);
    int e1 = has1 ? __builtin_amdgcn_readfirstlane(rowptr[d1 + 1]) : e0;

    const unsigned int* __restrict__ yb = (const unsigned int*)y16;  // 64 uints/row

    unsigned sv0 = yb[(long)d0 * 64 + lane];
    float ax0 = bflo(sv0), ay0 = bfhi(sv0);
    unsigned sv1 = yb[(long)(has1 ? d1 : d0) * 64 + lane];
    float ax1 = bflo(sv1), ay1 = bfhi(sv1);

    for (int win = b0; win < e1; win += 64) {
        int m = e1 - win;
        if (m > 64) m = 64;
        int c = col[win + lane];  // lanes >= m load garbage; never consumed
        int j = 0;
        for (; j + 8 <= m; j += 8) {
            int s0 = __builtin_amdgcn_readlane(c, j);
            int s1 = __builtin_amdgcn_readlane(c, j + 1);
            int s2 = __builtin_amdgcn_readlane(c, j + 2);
            int s3 = __builtin_amdgcn_readlane(c, j + 3);
            int s4 = __builtin_amdgcn_readlane(c, j + 4);
            int s5 = __builtin_amdgcn_readlane(c, j + 5);
            int s6 = __builtin_amdgcn_readlane(c, j + 6);
            int s7 = __builtin_amdgcn_readlane(c, j + 7);
            unsigned v0 = yb[(long)s0 * 64 + lane];
            unsigned v1 = yb[(long)s1 * 64 + lane];
            unsigned v2 = yb[(long)s2 * 64 + lane];
            unsigned v3 = yb[(long)s3 * 64 + lane];
            unsigned v4 = yb[(long)s4 * 64 + lane];
            unsigned v5 = yb[(long)s5 * 64 + lane];
            unsigned v6 = yb[(long)s6 * 64 + lane];
            unsigned v7 = yb[(long)s7 * 64 + lane];
#pragma unroll
            for (int k = 0; k < 8; k++) {
                unsigned vv = (k == 0) ? v0 : (k == 1) ? v1 : (k == 2) ? v2 : (k == 3) ? v3
                            : (k == 4) ? v4 : (k == 5) ? v5 : (k == 6) ? v6 : v7;
                float w0 = (win + j + k < e0) ? 1.f : 0.f;  // wave-uniform select
                float w1 = 1.f - w0;
                float lx = bflo(vv), ly = bfhi(vv);
                ax0 += lx * w0; ay0 += ly * w0;
                ax1 += lx * w1; ay1 += ly * w1;
            }
        }
        for (; j < m; j++) {
            int s = __builtin_amdgcn_readlane(c, j);
            unsigned vv = yb[(long)s * 64 + lane];
            float w0 = (win + j < e0) ? 1.f : 0.f;
            float w1 = 1.f - w0;
            float lx = bflo(vv), ly = bfhi(vv);
            ax0 += lx * w0; ay0 += ly * w0;
            ax1 += lx * w1; ay1 += ly * w1;
        }
    }

    float dinv0 = 1.f / (float)(e0 - b0 + 1);
    float dinv1 = 1.f / (float)(e1 - e0 + 1);
    ax0 *= dinv0; ay0 *= dinv0;
    ax1 *= dinv1; ay1 *= dinv1;

    bool act = lane < (D / 2);
    float nsq0 = act ? (ax0 * ax0 + ay0 * ay0) : 0.f;
    float nsq1 = act ? (ax1 * ax1 + ay1 * ay1) : 0.f;
    for (int off = 32; off; off >>= 1) {
        nsq0 += __shfl_xor(nsq0, off);
        nsq1 += __shfl_xor(nsq1, off);
    }
    float sc0 = invlp1 / fmaxf(sqrtf(nsq0), 1e-12f);
    float sc1 = invlp1 / fmaxf(sqrtf(nsq1), 1e-12f);

    if (write_x) {
        unsigned p0 = act ? ((unsigned)f2bf(ax0) | ((unsigned)f2bf(ay0) << 16)) : 0u;
        xnew16[(long)d0 * 64 + lane] = p0;
        if (has1) {
            unsigned p1 = act ? ((unsigned)f2bf(ax1) | ((unsigned)f2bf(ay1) << 16)) : 0u;
            xnew16[(long)d1 * 64 + lane] = p1;
        }
    }
    if (act) {
        float2 bv0 = *(const float2*)(basein + (long)d0 * D + lane * 2);
        float2 o0;
        o0.x = bv0.x * basescale + ax0 * sc0;
        o0.y = bv0.y * basescale + ay0 * sc0;
        *(float2*)(avg + (long)d0 * D + lane * 2) = o0;
        if (has1) {
            float2 bv1 = *(const float2*)(basein + (long)d1 * D + lane * 2);
            float2 o1;
            o1.x = bv1.x * basescale + ax1 * sc1;
            o1.y = bv1.y * basescale + ay1 * sc1;
            *(float2*)(avg + (long)d1 * D + lane * 2) = o1;
        }
    }
}

// ---------------- launcher ----------------

extern "C" void kernel_launch(void* const* d_in, const int* in_sizes, int n_in,
                              void* d_out, int out_size, void* d_ws, size_t ws_size,
                              hipStream_t stream) {
    const float* features = (const float*)d_in[0];
    const float* W        = (const float*)d_in[1];
    const int*   src      = (const int*)d_in[2];
    const int*   dstv     = (const int*)d_in[3];

    int N = in_sizes[0] / D;            // 50000
    int E = in_sizes[2];                // 800000
    int L = in_sizes[1] / (D * D);      // 2
    float invlp1 = 1.f / (float)(L + 1);
    int NBK = (N + BSIZE - 1) >> BSHIFT;

    char*  ws  = (char*)d_ws;
    size_t off = 0;
    auto alloc = [&](size_t bytes) -> void* {
        void* p = (void*)(ws + off);
        off += (bytes + 255) & ~(size_t)255;
        return p;
    };
    unsigned short* y16    = (unsigned short*)alloc((size_t)N * YSTRIDE * sizeof(unsigned short));
    unsigned*       x16    = (unsigned*)alloc((size_t)N * 64 * sizeof(unsigned));
    unsigned short* wpack  = (unsigned short*)alloc((size_t)L * 7 * 4 * 64 * 8 * sizeof(unsigned short));
    unsigned*       ebuf   = (unsigned*)alloc((size_t)E * sizeof(unsigned));
    int*            colb   = (int*)alloc((size_t)E * sizeof(int));
    int*            rowptr = (int*)alloc((size_t)(N + 1) * sizeof(int));
    int*            bcnt   = (int*)alloc((size_t)NBKMAX * sizeof(int));
    int*            boff   = (int*)alloc((size_t)(NBKMAX + 1) * sizeof(int));
    int*            bcur   = (int*)alloc((size_t)NBKMAX * sizeof(int));

    int nebk = (E + EPB - 1) / EPB;
    int wtot = L * 7 * 4 * 64;
    k_init<<<(max(wtot, NBKMAX) + 255) / 256, 256, 0, stream>>>(W, wpack, bcnt, wtot);
    k_bucketA<<<nebk, 256, 0, stream>>>(dstv, bcnt, E, NBK);
    k_scanB<<<1, 256, 0, stream>>>(bcnt, boff, bcur, NBK, E);
    k_bucketC<<<nebk, 256, 0, stream>>>(src, dstv, bcur, ebuf, E, NBK);
    k_bucketD<<<NBK, 256, 0, stream>>>(ebuf, boff, colb, rowptr, N, NBK, E);

    float* out = (float*)d_out;
    int nrowtiles  = (N + 15) / 16;
    int gemmblocks = (nrowtiles + 3) / 4;
    int spmmblocks = ((N + 1) / 2 + 3) / 4;
    for (int l = 0; l < L; l++) {
        if (l == 0)
            k_gemm_f32<<<gemmblocks, 256, 0, stream>>>(features, wpack, y16, N);
        else
            k_gemm_bf16<<<gemmblocks, 256, 0, stream>>>((const unsigned short*)x16,
                                                        wpack + (size_t)l * 7 * 4 * 64 * 8, y16, N);
        const float* basein = (l == 0) ? features : out;
        float bscale        = (l == 0) ? invlp1 : 1.f;
        int   write_x       = (l < L - 1) ? 1 : 0;
        k_spmm<<<spmmblocks, 256, 0, stream>>>(y16, rowptr, colb, basein, bscale, invlp1, write_x,
                                               x16, out, N);
    }
}